// Round 10
// baseline (101.337 us; speedup 1.0000x reference)
//
#include <hip/hip_runtime.h>
#include <hip/hip_bf16.h>
#include <math.h>

#define B 8
#define N 4096
#define D 256
#define BN (B*N)
#define NSUP 64       // 64-row supers per batch (1 super == 1 mfma block tile)
#define CAP 256       // bucket capacity (sizes ~Poisson(64); 256 = +24 sigma)

typedef __attribute__((ext_vector_type(8))) short bf16x8;
typedef __attribute__((ext_vector_type(4))) float f32x4;

#define GLD16(src, dst) __builtin_amdgcn_global_load_lds( \
    (const __attribute__((address_space(1))) void*)(src), \
    (__attribute__((address_space(3))) void*)(dst), 16, 0, 0)

__device__ __forceinline__ ushort bf16_hi(float x) {
  __hip_bfloat16 h = __float2bfloat16(x);
  return *(ushort*)&h;
}
__device__ __forceinline__ ushort bf16_lo(float x) {
  __hip_bfloat16 h = __float2bfloat16(x);
  float hf = __bfloat162float(h);
  __hip_bfloat16 l = __float2bfloat16(x - hf);
  return *(ushort*)&l;
}

// ---------------- K1: f1/f2 dots + zero rank/bcnt + W split (fused) ------------
__global__ __launch_bounds__(256) void k_f1f2w(const float* __restrict__ seq,
    const float* __restrict__ w1, const float* __restrict__ b1,
    const float* __restrict__ w2, const float* __restrict__ b2,
    const float* __restrict__ W, float* __restrict__ f1, float* __restrict__ f2,
    int* __restrict__ rank, int* __restrict__ bcnt, ushort* __restrict__ W3) {
  if (blockIdx.x >= BN/4) {
    int xb = blockIdx.x - BN/4;
    if (xb == 256) {                              // zero bucket counters
      if (threadIdx.x < 256) { bcnt[threadIdx.x] = 0; bcnt[256 + threadIdx.x] = 0; }
      return;
    }
    int n = xb;                                   // W -> W3t[n][768]=[Wh|Wl|Wh]
    int k = threadIdx.x;
    float x = W[(size_t)k * D + n];
    ushort hu = bf16_hi(x), lu = bf16_lo(x);
    W3[(size_t)n * 768 + k] = hu;
    W3[(size_t)n * 768 + 256 + k] = lu;
    W3[(size_t)n * 768 + 512 + k] = hu;
    return;
  }
  int wave = threadIdx.x >> 6;
  int lane = threadIdx.x & 63;
  long row = (long)blockIdx.x * 4 + wave;
  float4 v = ((const float4*)(seq + row * D))[lane];
  float4 a = ((const float4*)w1)[lane];
  float4 b = ((const float4*)w2)[lane];
  float s1 = v.x*a.x + v.y*a.y + v.z*a.z + v.w*a.w;
  float s2 = v.x*b.x + v.y*b.y + v.z*b.z + v.w*b.w;
  for (int off = 32; off; off >>= 1) {
    s1 += __shfl_xor(s1, off, 64);
    s2 += __shfl_xor(s2, off, 64);
  }
  if (lane == 0) {
    f1[row] = s1 + b1[0];
    f2[row] = s2 + b2[0];
    rank[row] = 0;
  }
}

// ---------------- K2a: partial rank counts (tiled O(N^2), 64-bit keys) ---------
__global__ __launch_bounds__(256) void k_rank_count(const float* __restrict__ f2,
    int* __restrict__ rank) {
  __shared__ unsigned long long skey[256];
  int b = blockIdx.z;
  int tid = threadIdx.x;
  const float* fb = f2 + (long)b * N;
  int p = blockIdx.y * 256 + tid;
  unsigned int up = __float_as_uint(fb[p]);
  up ^= (unsigned int)(((int)up >> 31) | 0x80000000);
  skey[tid] = ((unsigned long long)up << 12) | (unsigned)p;
  unsigned long long kj[4];
  int jbase = blockIdx.x * 1024;
  #pragma unroll
  for (int q = 0; q < 4; ++q) {
    int j = jbase + q * 256 + tid;
    unsigned int uj = __float_as_uint(fb[j]);
    uj ^= (unsigned int)(((int)uj >> 31) | 0x80000000);
    kj[q] = ((unsigned long long)uj << 12) | (unsigned)j;
  }
  __syncthreads();
  int c[4] = {0, 0, 0, 0};
  const ulonglong2* sk2 = (const ulonglong2*)skey;
  #pragma unroll 4
  for (int pp = 0; pp < 128; ++pp) {
    ulonglong2 kk = sk2[pp];
    #pragma unroll
    for (int q = 0; q < 4; ++q) {
      c[q] += (kk.x < kj[q]) ? 1 : 0;
      c[q] += (kk.y < kj[q]) ? 1 : 0;
    }
  }
  #pragma unroll
  for (int q = 0; q < 4; ++q)
    atomicAdd(&rank[(long)b * N + jbase + q * 256 + tid], c[q]);
}

// ---------------- K2b: scatter into sorted order -------------------------------
__global__ __launch_bounds__(256) void k_scatter(const float* __restrict__ f2,
    const int* __restrict__ rank, float* __restrict__ sF2, int* __restrict__ sIdx,
    float* __restrict__ e2lo, float* __restrict__ e2hi) {
  long idx = (long)blockIdx.x * 256 + threadIdx.x;
  int b = (int)(idx >> 12);
  int j = (int)(idx & (N - 1));
  float v = f2[idx];
  int cnt = rank[idx];
  long o = (long)b * N + cnt;
  sF2[o] = v;
  sIdx[o] = j;
  e2lo[o] = expf(0.01f * v);
  e2hi[o] = expf(v);
}

// ---------------- K2c: bucket rows by k-super (binary search on sF2) -----------
__global__ __launch_bounds__(256) void k_bucket(const float* __restrict__ f1,
    const float* __restrict__ sF2, int* __restrict__ bcnt,
    unsigned* __restrict__ blist) {
  int i = blockIdx.x * 256 + threadIdx.x;          // 0..BN-1
  int b = i >> 12, il = i & 4095;
  float t = -f1[i];
  const float* sb = sF2 + ((size_t)b << 12);
  int lo = 0, hi = N;
  while (lo < hi) { int mid = (lo + hi) >> 1; if (sb[mid] <= t) lo = mid + 1; else hi = mid; }
  int k = lo;                                       // 0..4096
  int s = k >> 6; if (s > 63) s = 63;               // k==4096 -> bucket 63, rloc 64
  int pos = atomicAdd(&bcnt[b * 64 + s], 1);
  if (pos < CAP) blist[(size_t)(b * 64 + s) * CAP + pos] = ((unsigned)k << 12) | (unsigned)il;
}

// ---------------- K3: split-bf16 MFMA GEMM -> Vs + per-super totals ------------
// A segs [Ah|Ah|Al] x W3=[Wh|Wl|Wh]. No gran-1 prefix writes (R8 lesson: Rel
// round-trip was 134MB); just Vs + in-register weighted super totals.
__global__ __launch_bounds__(256) void k_mfma(const float* __restrict__ seq,
    const int* __restrict__ sIdx, const ushort* __restrict__ W3,
    const float* __restrict__ e2lo, const float* __restrict__ e2hi,
    float* __restrict__ Vs, float* __restrict__ SupBaseLo,
    float* __restrict__ SupBaseHi, float* __restrict__ SupZlo,
    float* __restrict__ SupZhi) {
  __shared__ __align__(16) char smem[64*72*2 + 256*64*2];   // As + Bs (~42KB)
  __shared__ float partLo[2][256], partHi[2][256];
  __shared__ float wlS[64], whS[64];
  ushort (*As)[72] = (ushort(*)[72])smem;
  ushort (*Bs)[64] = (ushort(*)[64])(smem + 64 * 72 * 2);
  int tid = threadIdx.x;
  int wid = tid >> 6, lane = tid & 63;
  int mBase = blockIdx.x * 64;
  int b = mBase >> 12;
  int ar = tid >> 2, aq = tid & 3;
  const float* aSrc = seq + (((size_t)(b << 12)) + sIdx[mBase + ar]) * D + aq * 16;
  int lr = lane >> 3;
  int lcSw = (((lane & 7) ^ (lr & 7))) * 8;
  int wr = wid >> 1, wc = wid & 1, g = lane >> 4, r16 = lane & 15;
  int bswz = r16 & 7;

  f32x4 acc[2][8];
  #pragma unroll
  for (int m = 0; m < 2; ++m)
    #pragma unroll
    for (int n = 0; n < 8; ++n) {
      acc[m][n][0] = 0.f; acc[m][n][1] = 0.f; acc[m][n][2] = 0.f; acc[m][n][3] = 0.f;
    }

  float4 xv[4];
  #pragma unroll
  for (int i = 0; i < 4; ++i) xv[i] = *(const float4*)(aSrc + i * 4);  // kt=0

  for (int kt = 0; kt < 768; kt += 64) {
    ushort ou[16];
    if (kt < 512) {
      #pragma unroll
      for (int i = 0; i < 4; ++i) {
        ou[i*4+0] = bf16_hi(xv[i].x); ou[i*4+1] = bf16_hi(xv[i].y);
        ou[i*4+2] = bf16_hi(xv[i].z); ou[i*4+3] = bf16_hi(xv[i].w);
      }
    } else {
      #pragma unroll
      for (int i = 0; i < 4; ++i) {
        ou[i*4+0] = bf16_lo(xv[i].x); ou[i*4+1] = bf16_lo(xv[i].y);
        ou[i*4+2] = bf16_lo(xv[i].z); ou[i*4+3] = bf16_lo(xv[i].w);
      }
    }
    __syncthreads();
    #pragma unroll
    for (int i = 0; i < 4; ++i)
      *(ushort4*)&As[ar][aq * 16 + i * 4] =
          make_ushort4(ou[i*4+0], ou[i*4+1], ou[i*4+2], ou[i*4+3]);
    #pragma unroll
    for (int q = 0; q < 8; ++q) {
      int r0 = q * 32 + wid * 8;
      GLD16(W3 + (size_t)(r0 + lr) * 768 + kt + lcSw, &Bs[r0][0]);
    }
    if (kt < 704) {                        // prefetch next A tile (issue only)
      int nacol = (kt + 64) & 255;
      #pragma unroll
      for (int i = 0; i < 4; ++i) xv[i] = *(const float4*)(aSrc + nacol + i * 4);
    }
    __syncthreads();
    #pragma unroll
    for (int kk = 0; kk < 64; kk += 32) {
      bf16x8 av[2], bv[8];
      #pragma unroll
      for (int m = 0; m < 2; ++m)
        av[m] = *(const bf16x8*)&As[wr*32 + m*16 + r16][kk + g*8];
      int jb = (kk >> 3) + g;
      int jj = jb ^ bswz;
      #pragma unroll
      for (int n = 0; n < 8; ++n) {
        int row = wc*128 + n*16 + r16;
        bv[n] = *(const bf16x8*)((const char*)Bs + row * 128 + jj * 16);
      }
      #pragma unroll
      for (int m = 0; m < 2; ++m)
        #pragma unroll
        for (int n = 0; n < 8; ++n)
          acc[m][n] = __builtin_amdgcn_mfma_f32_16x16x32_bf16(av[m], bv[n], acc[m][n], 0, 0, 0);
    }
  }

  // ---- epilogue: Vs store + in-register weighted super totals ----
  size_t rb = (size_t)mBase;
  int s = (mBase >> 6) & 63;
  if (tid < 64) { wlS[tid] = e2lo[rb + tid]; whS[tid] = e2hi[rb + tid]; }
  #pragma unroll
  for (int m = 0; m < 2; ++m)
    #pragma unroll
    for (int n = 0; n < 8; ++n) {
      int col = wc*128 + n*16 + r16;
      #pragma unroll
      for (int j = 0; j < 4; ++j) {
        int row = mBase + wr*32 + m*16 + g*4 + j;
        Vs[(size_t)row * D + col] = acc[m][n][j];
      }
    }
  __syncthreads();
  float plo[8], phi[8];
  #pragma unroll
  for (int n = 0; n < 8; ++n) { plo[n] = 0.f; phi[n] = 0.f; }
  #pragma unroll
  for (int m = 0; m < 2; ++m)
    #pragma unroll
    for (int j = 0; j < 4; ++j) {
      int lr2 = wr*32 + m*16 + g*4 + j;            // block-local row
      float wL = wlS[lr2], wH = whS[lr2];
      #pragma unroll
      for (int n = 0; n < 8; ++n) {
        plo[n] += wL * acc[m][n][j];
        phi[n] += wH * acc[m][n][j];
      }
    }
  #pragma unroll
  for (int n = 0; n < 8; ++n) {                    // reduce over g (lane bits 4,5)
    plo[n] += __shfl_xor(plo[n], 16, 64); plo[n] += __shfl_xor(plo[n], 32, 64);
    phi[n] += __shfl_xor(phi[n], 16, 64); phi[n] += __shfl_xor(phi[n], 32, 64);
  }
  if (g == 0) {
    #pragma unroll
    for (int n = 0; n < 8; ++n) {
      partLo[wr][wc*128 + n*16 + r16] = plo[n];
      partHi[wr][wc*128 + n*16 + r16] = phi[n];
    }
  }
  __syncthreads();
  SupBaseLo[((size_t)b * 64 + s) * D + tid] = partLo[0][tid] + partLo[1][tid];
  SupBaseHi[((size_t)b * 64 + s) * D + tid] = partHi[0][tid] + partHi[1][tid];
  if (tid < 64) {                                  // z totals: wave-0 reduce lo
    float z = wlS[tid];
    for (int off = 1; off < 64; off <<= 1) z += __shfl_xor(z, off, 64);
    if (tid == 0) SupZlo[b * 64 + s] = z;
  } else if (tid < 128) {                          // wave-1 reduce hi
    float z = whS[tid - 64];
    for (int off = 1; off < 64; off <<= 1) z += __shfl_xor(z, off, 64);
    if (tid == 64) SupZhi[b * 64 + s] = z;
  }
}

// ---------------- K4: walk supers, emit bucketed rows --------------------------
// Block (b,s): start from sum of super totals < s, stream 64 Vs rows updating
// running S/z, emit each bucketed output row when walk reaches its k.
__global__ __launch_bounds__(256) void k_walk(const float* __restrict__ f1,
    const float* __restrict__ e2lo, const float* __restrict__ e2hi,
    const float* __restrict__ Vs, const float* __restrict__ SupBaseLo,
    const float* __restrict__ SupBaseHi, const float* __restrict__ SupZlo,
    const float* __restrict__ SupZhi, const int* __restrict__ bcnt,
    const unsigned* __restrict__ blist, const float* __restrict__ bias,
    float* __restrict__ out) {
  int s = blockIdx.x & 63, b = blockIdx.x >> 6;
  int cnt = bcnt[b * 64 + s];
  if (cnt == 0) return;
  if (cnt > CAP) cnt = CAP;
  int tid = threadIdx.x;
  __shared__ float f1a[CAP], f1c[CAP];
  __shared__ unsigned sorted_[CAP];
  __shared__ int binStart[66];
  __shared__ int binOff[65];
  __shared__ float wl[64], wh[64];

  // base sums over supers (per-dim d=tid) + scalar z bases
  float baseLo = 0.f, baseHi = 0.f, totHi = 0.f;
  float zbLo = 0.f, zbHi = 0.f, ztHi = 0.f;
  const float* sbl = SupBaseLo + (size_t)b * 64 * D + tid;
  const float* sbh = SupBaseHi + (size_t)b * 64 * D + tid;
  #pragma unroll 8
  for (int sp = 0; sp < 64; ++sp) {
    float l = sbl[(size_t)sp * D];
    float h = sbh[(size_t)sp * D];
    float zl = SupZlo[b * 64 + sp], zh = SupZhi[b * 64 + sp];
    if (sp < s) { baseLo += l; baseHi += h; zbLo += zl; zbHi += zh; }
    totHi += h; ztHi += zh;
  }

  size_t rb = ((size_t)b << 12) + (size_t)s * 64;
  if (tid < 64) { wl[tid] = e2lo[rb + tid]; wh[tid] = e2hi[rb + tid]; }
  if (tid < 65) binOff[tid] = 0;
  __syncthreads();
  unsigned pk = 0; int myr = -1;
  if (tid < cnt) {
    pk = blist[(size_t)(b * 64 + s) * CAP + tid];
    myr = (int)(pk >> 12) - s * 64;                // 0..64
    atomicAdd(&binOff[myr], 1);
  }
  __syncthreads();
  if (tid < 64) {                                  // exclusive scan of bins 0..63
    int v = binOff[tid];
    int x = v;
    #pragma unroll
    for (int off = 1; off < 64; off <<= 1) {
      int y = __shfl_up(x, off, 64);
      if (tid >= off) x += y;
    }
    binStart[tid] = x - v;
    if (tid == 63) { binStart[64] = x; binStart[65] = x + binOff[64]; }
  }
  __syncthreads();
  if (tid < 65) binOff[tid] = 0;
  __syncthreads();
  if (tid < cnt) {
    int pos = binStart[myr] + atomicAdd(&binOff[myr], 1);
    sorted_[pos] = pk;
  }
  __syncthreads();
  if (tid < cnt) {
    unsigned q = sorted_[tid];
    int io = q & 4095;
    float f = f1[((size_t)b << 12) + io];
    f1a[tid] = expf(f);
    f1c[tid] = expf(0.01f * f);
  }
  __syncthreads();

  float Slo = baseLo, Shi = baseHi;
  float zlo = zbLo, zhi = zbHi;
  const float* vrow = Vs + rb * D + tid;
  float bsc = bias[0];
  for (int r16b = 0; r16b < 64; r16b += 16) {
    float vv[16];
    #pragma unroll
    for (int u = 0; u < 16; ++u) vv[u] = vrow[(size_t)(r16b + u) * D];
    #pragma unroll
    for (int u = 0; u < 16; ++u) {
      int r = r16b + u;
      for (int e = binStart[r]; e < binStart[r + 1]; ++e) {
        unsigned q = sorted_[e];
        int io = q & 4095;
        float a = f1a[e], c2 = f1c[e];
        float Z = a * (ztHi - zhi) + c2 * zlo;
        float o = (a * (totHi - Shi) + c2 * Slo) / Z + bsc;
        out[((((size_t)b << 12) + io) << 8) + tid] = fmaxf(o, 0.f);
      }
      float wL = wl[r], wH = wh[r];
      Slo += wL * vv[u]; Shi += wH * vv[u];
      zlo += wL; zhi += wH;
    }
  }
  for (int e = binStart[64]; e < binStart[65]; ++e) {   // k == 4096 (s == 63)
    unsigned q = sorted_[e];
    int io = q & 4095;
    float a = f1a[e], c2 = f1c[e];
    float Z = a * (ztHi - zhi) + c2 * zlo;
    float o = (a * (totHi - Shi) + c2 * Slo) / Z + bsc;
    out[((((size_t)b << 12) + io) << 8) + tid] = fmaxf(o, 0.f);
  }
}

// ---------------- launch -------------------------------------------------------
extern "C" void kernel_launch(void* const* d_in, const int* in_sizes, int n_in,
                              void* d_out, int out_size, void* d_ws, size_t ws_size,
                              hipStream_t stream) {
  const float* seq  = (const float*)d_in[0];
  const float* Wf   = (const float*)d_in[1];
  const float* w1   = (const float*)d_in[2];
  const float* b1   = (const float*)d_in[3];
  const float* w2   = (const float*)d_in[4];
  const float* b2   = (const float*)d_in[5];
  const float* bias = (const float*)d_in[6];
  float* out = (float*)d_out;

  size_t needFloats = (size_t)7*BN + (size_t)BN*D + 2*(size_t)B*NSUP*D
                    + 2*(size_t)B*NSUP + (size_t)B*NSUP + (size_t)B*NSUP*CAP;
  size_t need = needFloats * 4 + (size_t)256 * 768 * 2;
  if (ws_size < need) return;

  float* f1   = (float*)d_ws;
  float* f2   = f1 + BN;
  float* sF2  = f2 + BN;
  float* e2lo = sF2 + BN;
  float* e2hi = e2lo + BN;
  int* sIdx   = (int*)(e2hi + BN);
  int* rank   = sIdx + BN;
  float* Vs   = (float*)(rank + BN);
  float* SupBaseLo = Vs + (size_t)BN * D;
  float* SupBaseHi = SupBaseLo + (size_t)B * NSUP * D;
  float* SupZlo = SupBaseHi + (size_t)B * NSUP * D;
  float* SupZhi = SupZlo + B * NSUP;
  int* bcnt     = (int*)(SupZhi + B * NSUP);
  unsigned* blist = (unsigned*)(bcnt + B * NSUP);
  ushort* W3 = (ushort*)(blist + (size_t)B * NSUP * CAP);

  k_f1f2w<<<dim3(BN/4 + 257), 256, 0, stream>>>(seq, w1, b1, w2, b2, Wf,
      f1, f2, rank, bcnt, W3);
  k_rank_count<<<dim3(N/1024, N/256, B), 256, 0, stream>>>(f2, rank);
  k_scatter<<<dim3(BN/256), 256, 0, stream>>>(f2, rank, sF2, sIdx, e2lo, e2hi);
  k_bucket<<<dim3(BN/256), 256, 0, stream>>>(f1, sF2, bcnt, blist);
  k_mfma<<<dim3(BN/64), 256, 0, stream>>>(seq, sIdx, W3, e2lo, e2hi,
      Vs, SupBaseLo, SupBaseHi, SupZlo, SupZhi);
  k_walk<<<dim3(B * NSUP), 256, 0, stream>>>(f1, e2lo, e2hi, Vs,
      SupBaseLo, SupBaseHi, SupZlo, SupZhi, bcnt, blist, bias, out);
}